// Round 10
// baseline (84.494 us; speedup 1.0000x reference)
//
#include <hip/hip_runtime.h>
#include <hip/hip_bf16.h>

#define NN 50000
#define NE 800000

typedef __attribute__((ext_vector_type(4))) float f32x4;
typedef __attribute__((ext_vector_type(8))) __bf16 bf16x8;

__device__ __forceinline__ float wred64(float v) {
    v += __shfl_xor(v, 32, 64);
    v += __shfl_xor(v, 16, 64);
    v += __shfl_xor(v, 8, 64);
    v += __shfl_xor(v, 4, 64);
    v += __shfl_xor(v, 2, 64);
    v += __shfl_xor(v, 1, 64);
    return v;
}

__device__ __forceinline__ float arcosh_f(float z) {
    z = fmaxf(z, 1.0f + 1e-7f);
    return logf(z + sqrtf(z * z - 1.0f));
}

// ---------------------------------------------------------------------------
// prep: pack W^T into MFMA B-fragment-linear order as bf16 hi/lo pair.
// ---------------------------------------------------------------------------
__global__ void prep_kernel(const float* __restrict__ weight, const float* __restrict__ bias,
                            ushort* __restrict__ WfHi, ushort* __restrict__ WfLo,
                            float* __restrict__ biasP) {
    int t8 = blockIdx.x * 256 + threadIdx.x;   // 0..2047 over grid of 8 blocks
    int l = t8 & 63, f = t8 >> 6;
    int t = f & 3, jt = f >> 2;
    int g = l >> 4, r = l & 15;
    int col = jt * 16 + r;
    #pragma unroll
    for (int i = 0; i < 8; ++i) {
        int k = 32 * g + 8 * t + i;
        float v = (col < 127) ? weight[col * 128 + k] : 0.0f;
        __bf16 h = (__bf16)v;
        float lo = v - (float)h;
        __bf16 lb = (__bf16)lo;
        WfHi[t8 * 8 + i] = __builtin_bit_cast(unsigned short, h);
        WfLo[t8 * 8 + i] = __builtin_bit_cast(unsigned short, lb);
    }
    if (t8 < 128) biasP[t8] = (t8 < 127) ? bias[t8] : 0.0f;
}

// ---------------------------------------------------------------------------
// rowptr[r] = first edge with row >= r (rows sorted)
// ---------------------------------------------------------------------------
__global__ void rowptr_kernel(const int* __restrict__ row, int* __restrict__ rowptr) {
    int e = blockIdx.x * 256 + threadIdx.x;
    if (e >= NE) return;
    int r1 = row[e];
    int r0 = (e == 0) ? -1 : row[e - 1];
    for (int r = r0 + 1; r <= r1; ++r) rowptr[r] = e;
    if (e == NE - 1) {
        for (int r = r1 + 1; r <= NN; ++r) rowptr[r] = NE;
    }
}

// ---------------------------------------------------------------------------
// Stage 1 via MFMA (bf16x3 compensated): h = exp_map_zero([0, W@log0(x)+b])
// Output: hhb[node][128] bf16 (slot j = tail comp j, j<127; slot 127 = 0)
//         hhead[node]    fp32 head (the precision-critical component)
// ---------------------------------------------------------------------------
__global__ __launch_bounds__(256) void transform_kernel(
        const float* __restrict__ x, const ushort* __restrict__ Wf /* hi|lo 64KB */,
        const float* __restrict__ biasP, ushort* __restrict__ hhb,
        float* __restrict__ hhead) {
    __shared__ __align__(16) ushort WF[32768];   // 64 KB: [0,16384) hi, rest lo

    const int tid = threadIdx.x;
    #pragma unroll
    for (int i = 0; i < 16; ++i)
        ((float4*)WF)[i * 256 + tid] = ((const float4*)Wf)[i * 256 + tid];

    const int lane = tid & 63, w = tid >> 6;
    const int g = lane >> 4, r = lane & 15;
    const int nodeA = blockIdx.x * 64 + w * 16 + r;   // A-fragment row

    float xv[32];
    float x0 = 1.0f;
    if (nodeA < NN) {
        const float* xp = x + (long)nodeA * 129;
        x0 = xp[0];
        __builtin_memcpy(xv, xp + 1 + 32 * g, 128);
    } else {
        #pragma unroll
        for (int i = 0; i < 32; ++i) xv[i] = 0.0f;
    }
    // input invariant: x0 = sqrt(1 + sum tail^2)  ->  ssq = x0^2 - 1
    float dist = arcosh_f(x0);
    float sc = dist / sqrtf(fmaxf(x0 * x0 - 1.0f, 1e-6f));

    bf16x8 ah[4], al[4];
    #pragma unroll
    for (int t = 0; t < 4; ++t) {
        #pragma unroll
        for (int i = 0; i < 8; ++i) {
            float v = sc * xv[8 * t + i];
            __bf16 h = (__bf16)v;
            ah[t][i] = h;
            al[t][i] = (__bf16)(v - (float)h);
        }
    }
    __syncthreads();

    f32x4 acc[8];
    #pragma unroll
    for (int jt = 0; jt < 8; ++jt) acc[jt] = (f32x4){0.0f, 0.0f, 0.0f, 0.0f};

    #pragma unroll
    for (int jt = 0; jt < 8; ++jt) {
        #pragma unroll
        for (int t = 0; t < 4; ++t) {
            const int f = jt * 4 + t;
            bf16x8 bh = *(const bf16x8*)&WF[(f * 64 + lane) * 8];
            bf16x8 bl = *(const bf16x8*)&WF[16384 + (f * 64 + lane) * 8];
            acc[jt] = __builtin_amdgcn_mfma_f32_16x16x32_bf16(al[t], bh, acc[jt], 0, 0, 0);
            acc[jt] = __builtin_amdgcn_mfma_f32_16x16x32_bf16(ah[t], bl, acc[jt], 0, 0, 0);
            acc[jt] = __builtin_amdgcn_mfma_f32_16x16x32_bf16(ah[t], bh, acc[jt], 0, 0, 0);
        }
    }

    float bv[8];
    #pragma unroll
    for (int jt = 0; jt < 8; ++jt) bv[jt] = biasP[jt * 16 + r];

    #pragma unroll
    for (int i = 0; i < 4; ++i) {
        float m[8];
        float p = 0.0f;
        #pragma unroll
        for (int jt = 0; jt < 8; ++jt) {
            m[jt] = acc[jt][i] + bv[jt];
            p = fmaf(m[jt], m[jt], p);
        }
        p += __shfl_xor(p, 1, 64);
        p += __shfl_xor(p, 2, 64);
        p += __shfl_xor(p, 4, 64);
        p += __shfl_xor(p, 8, 64);        // p = sum_{j<127} mx_j^2
        float n = sqrtf(fmaxf(p, 1e-6f));
        float rr = sinhf(fminf(n, 50.0f)) / n;
        int node = blockIdx.x * 64 + w * 16 + g * 4 + i;
        if (node < NN) {
            #pragma unroll
            for (int jt = 0; jt < 8; ++jt) {
                int j = jt * 16 + r;
                float vv = rr * m[jt];
                ushort us = (j == 127) ? (ushort)0
                          : __builtin_bit_cast(unsigned short, (__bf16)vv);
                hhb[node * 128 + j] = us;
            }
            if (r == 15) hhead[node] = sqrtf(1.0f + rr * rr * p);
        }
    }
}

// ---------------------------------------------------------------------------
// Stage 2+3 fused: segment gather-sum (bf16 rows + fp32 head), Lorentz
// centroid normalize, hyp_act. One wave per node.
// Address-minimized: per 4-edge iteration,
//   - col/val/head loaded by 4 ACTIVE lanes only (lane 16g <- edge e+g):
//     exec-masked lanes generate no addresses -> 12 addrs instead of 192.
//   - col/val broadcast to each 16-lane group via ds_swizzle (and-mask 0x10).
//   - row gather: lane (g,r) loads dwordx4 = comps r*8..r*8+7 of edge e+g
//     (64 addrs, irreducible for 4 x 256B rows).
// Per-lane accumulators sf[j] (comp r*8+j, edges == g mod 4) merged by
// shfl_xor(16,32); head partials live on lanes 16g, summed by wred64.
// ---------------------------------------------------------------------------
__global__ __launch_bounds__(256) void centroid_act_kernel(
        const ushort* __restrict__ hhb, const float* __restrict__ hhead,
        const float* __restrict__ val, const int* __restrict__ col,
        const int* __restrict__ rowptr, float* __restrict__ out) {
    const int lane = threadIdx.x & 63;
    const int node = blockIdx.x * 4 + (threadIdx.x >> 6);
    const int g = lane >> 4, r = lane & 15;
    const int lo = rowptr[node], hi = rowptr[node + 1];

    float sf[8];
    #pragma unroll
    for (int j = 0; j < 8; ++j) sf[j] = 0.0f;
    float s0p = 0.0f;

    for (int e = lo; e < hi; e += 4) {
        const int m = hi - e;
        int cc = 0; float vv = 0.0f;
        if (r == 0 && g < m) {                  // 4 active lanes: 16g
            cc = col[e + g];
            vv = val[e + g];
            s0p = fmaf(vv, hhead[cc], s0p);     // head: 4 addresses
        }
        const int   cg = __builtin_amdgcn_ds_swizzle(cc, 0x0010);
        const float vg = __builtin_bit_cast(float,
            __builtin_amdgcn_ds_swizzle(__builtin_bit_cast(int, vv), 0x0010));

        const uint4 u = *(const uint4*)((const char*)hhb + ((long)cg << 8) + (r << 4));
        sf[0] = fmaf(vg, __builtin_bit_cast(float, u.x << 16), sf[0]);
        sf[1] = fmaf(vg, __builtin_bit_cast(float, u.x & 0xffff0000u), sf[1]);
        sf[2] = fmaf(vg, __builtin_bit_cast(float, u.y << 16), sf[2]);
        sf[3] = fmaf(vg, __builtin_bit_cast(float, u.y & 0xffff0000u), sf[3]);
        sf[4] = fmaf(vg, __builtin_bit_cast(float, u.z << 16), sf[4]);
        sf[5] = fmaf(vg, __builtin_bit_cast(float, u.z & 0xffff0000u), sf[5]);
        sf[6] = fmaf(vg, __builtin_bit_cast(float, u.w << 16), sf[6]);
        sf[7] = fmaf(vg, __builtin_bit_cast(float, u.w & 0xffff0000u), sf[7]);
    }

    // merge the 4 edge-groups: sf[j] -> full sum for comp r*8+j (all lanes)
    #pragma unroll
    for (int j = 0; j < 8; ++j) {
        sf[j] += __shfl_xor(sf[j], 16, 64);
        sf[j] += __shfl_xor(sf[j], 32, 64);
    }
    float s0 = wred64(s0p);                       // each edge counted once

    // tsum = sum over all 127 tail comps of s_f^2 (slot 127 pad is 0)
    float p2 = 0.0f;
    #pragma unroll
    for (int j = 0; j < 8; ++j) p2 = fmaf(sf[j], sf[j], p2);
    p2 += __shfl_xor(p2, 1, 64);
    p2 += __shfl_xor(p2, 2, 64);
    p2 += __shfl_xor(p2, 4, 64);
    p2 += __shfl_xor(p2, 8, 64);                   // reduce over r (g's identical)
    const float tsum = p2;

    const float inner = tsum - s0 * s0;
    const float coef = 1.0f / sqrtf(fmaxf(fabsf(inner), 1e-6f));
    const float h20 = coef * s0;

    // hyp_act = exp_map_zero(relu(log_map_zero(h2)))
    const float dist = arcosh_f(h20);
    const float tsq = coef * coef * tsum;
    const float scl = dist / sqrtf(fmaxf(tsq, 1e-6f));

    float uu[8];
    float p3 = 0.0f;
    #pragma unroll
    for (int j = 0; j < 8; ++j) {
        uu[j] = fmaxf(scl * coef * sf[j], 0.0f);
        p3 = fmaf(uu[j], uu[j], p3);
    }
    p3 += __shfl_xor(p3, 1, 64);
    p3 += __shfl_xor(p3, 2, 64);
    p3 += __shfl_xor(p3, 4, 64);
    p3 += __shfl_xor(p3, 8, 64);
    const float S = p3;
    const float n = sqrtf(fmaxf(S, 1e-6f));
    const float rr = sinhf(fminf(n, 50.0f)) / n;

    // lane l writes comps c1 = r*8+2g, c2 = c1+1 (c2==127 -> head to out[0])
    const float ua = (g < 2) ? ((g == 0) ? uu[0] : uu[2]) : ((g == 2) ? uu[4] : uu[6]);
    const float ub = (g < 2) ? ((g == 0) ? uu[1] : uu[3]) : ((g == 2) ? uu[5] : uu[7]);
    const int c1 = r * 8 + 2 * g;
    float* op = out + (long)node * 128;
    op[1 + c1] = rr * ua;
    if (c1 + 1 < 127) op[2 + c1] = rr * ub;
    else              op[0] = sqrtf(1.0f + rr * rr * S);   // lane 63
}

extern "C" void kernel_launch(void* const* d_in, const int* in_sizes, int n_in,
                              void* d_out, int out_size, void* d_ws, size_t ws_size,
                              hipStream_t stream) {
    const float* x       = (const float*)d_in[0];
    const float* weight  = (const float*)d_in[1];
    const float* bias    = (const float*)d_in[2];
    const float* adj_val = (const float*)d_in[3];
    const int*   adj_row = (const int*)d_in[4];
    const int*   adj_col = (const int*)d_in[5];
    float* out = (float*)d_out;

    char* ws = (char*)d_ws;
    ushort* hhb    = (ushort*)ws;                   // 12,800,000 B
    float*  hhead  = (float*)(ws + 12800000);       // 200,000 B
    int*    rowptr = (int*)(ws + 13000000);         // 200,004 B
    ushort* WfHi   = (ushort*)(ws + 13200192);      // 32,768 B
    ushort* WfLo   = (ushort*)(ws + 13232960);      // 32,768 B
    float*  biasP  = (float*)(ws + 13265728);       // 512 B

    prep_kernel<<<8, 256, 0, stream>>>(weight, bias, WfHi, WfLo, biasP);
    rowptr_kernel<<<(NE + 255) / 256, 256, 0, stream>>>(adj_row, rowptr);
    transform_kernel<<<(NN + 63) / 64, 256, 0, stream>>>(x, WfHi, biasP, hhb, hhead);
    centroid_act_kernel<<<NN / 4, 256, 0, stream>>>(hhb, hhead, adj_val, adj_col, rowptr, out);
}

// Round 11
// 68.949 us; speedup vs baseline: 1.2254x; 1.2254x over previous
//
#include <hip/hip_runtime.h>
#include <hip/hip_bf16.h>

#define NN 50000
#define NE 800000

typedef __attribute__((ext_vector_type(4))) float f32x4;
typedef __attribute__((ext_vector_type(8))) __bf16 bf16x8;

__device__ __forceinline__ float wred64(float v) {
    v += __shfl_xor(v, 32, 64);
    v += __shfl_xor(v, 16, 64);
    v += __shfl_xor(v, 8, 64);
    v += __shfl_xor(v, 4, 64);
    v += __shfl_xor(v, 2, 64);
    v += __shfl_xor(v, 1, 64);
    return v;
}

__device__ __forceinline__ float arcosh_f(float z) {
    z = fmaxf(z, 1.0f + 1e-7f);
    return logf(z + sqrtf(z * z - 1.0f));
}

// ---------------------------------------------------------------------------
// prep: pack W^T into MFMA B-fragment-linear order as bf16 hi/lo pair.
// ---------------------------------------------------------------------------
__global__ void prep_kernel(const float* __restrict__ weight, const float* __restrict__ bias,
                            ushort* __restrict__ WfHi, ushort* __restrict__ WfLo,
                            float* __restrict__ biasP) {
    int t8 = blockIdx.x * 256 + threadIdx.x;   // 0..2047 over grid of 8 blocks
    int l = t8 & 63, f = t8 >> 6;
    int t = f & 3, jt = f >> 2;
    int g = l >> 4, r = l & 15;
    int col = jt * 16 + r;
    #pragma unroll
    for (int i = 0; i < 8; ++i) {
        int k = 32 * g + 8 * t + i;
        float v = (col < 127) ? weight[col * 128 + k] : 0.0f;
        __bf16 h = (__bf16)v;
        float lo = v - (float)h;
        __bf16 lb = (__bf16)lo;
        WfHi[t8 * 8 + i] = __builtin_bit_cast(unsigned short, h);
        WfLo[t8 * 8 + i] = __builtin_bit_cast(unsigned short, lb);
    }
    if (t8 < 128) biasP[t8] = (t8 < 127) ? bias[t8] : 0.0f;
}

// ---------------------------------------------------------------------------
// rowptr[r] = first edge with row >= r (rows sorted)
// ---------------------------------------------------------------------------
__global__ void rowptr_kernel(const int* __restrict__ row, int* __restrict__ rowptr) {
    int e = blockIdx.x * 256 + threadIdx.x;
    if (e >= NE) return;
    int r1 = row[e];
    int r0 = (e == 0) ? -1 : row[e - 1];
    for (int r = r0 + 1; r <= r1; ++r) rowptr[r] = e;
    if (e == NE - 1) {
        for (int r = r1 + 1; r <= NN; ++r) rowptr[r] = NE;
    }
}

// ---------------------------------------------------------------------------
// Stage 1 via MFMA (bf16x3 compensated): h = exp_map_zero([0, W@log0(x)+b])
// Output: hhb[node][128] bf16 (slot j = tail comp j, j<127; slot 127 = 0)
//         hhead[node]    fp32 head (the precision-critical component)
// ---------------------------------------------------------------------------
__global__ __launch_bounds__(256) void transform_kernel(
        const float* __restrict__ x, const ushort* __restrict__ Wf /* hi|lo 64KB */,
        const float* __restrict__ biasP, ushort* __restrict__ hhb,
        float* __restrict__ hhead) {
    __shared__ __align__(16) ushort WF[32768];   // 64 KB: [0,16384) hi, rest lo

    const int tid = threadIdx.x;
    #pragma unroll
    for (int i = 0; i < 16; ++i)
        ((float4*)WF)[i * 256 + tid] = ((const float4*)Wf)[i * 256 + tid];

    const int lane = tid & 63, w = tid >> 6;
    const int g = lane >> 4, r = lane & 15;
    const int nodeA = blockIdx.x * 64 + w * 16 + r;   // A-fragment row

    float xv[32];
    float x0 = 1.0f;
    if (nodeA < NN) {
        const float* xp = x + (long)nodeA * 129;
        x0 = xp[0];
        __builtin_memcpy(xv, xp + 1 + 32 * g, 128);
    } else {
        #pragma unroll
        for (int i = 0; i < 32; ++i) xv[i] = 0.0f;
    }
    // input invariant: x0 = sqrt(1 + sum tail^2)  ->  ssq = x0^2 - 1
    float dist = arcosh_f(x0);
    float sc = dist / sqrtf(fmaxf(x0 * x0 - 1.0f, 1e-6f));

    bf16x8 ah[4], al[4];
    #pragma unroll
    for (int t = 0; t < 4; ++t) {
        #pragma unroll
        for (int i = 0; i < 8; ++i) {
            float v = sc * xv[8 * t + i];
            __bf16 h = (__bf16)v;
            ah[t][i] = h;
            al[t][i] = (__bf16)(v - (float)h);
        }
    }
    __syncthreads();

    f32x4 acc[8];
    #pragma unroll
    for (int jt = 0; jt < 8; ++jt) acc[jt] = (f32x4){0.0f, 0.0f, 0.0f, 0.0f};

    #pragma unroll
    for (int jt = 0; jt < 8; ++jt) {
        #pragma unroll
        for (int t = 0; t < 4; ++t) {
            const int f = jt * 4 + t;
            bf16x8 bh = *(const bf16x8*)&WF[(f * 64 + lane) * 8];
            bf16x8 bl = *(const bf16x8*)&WF[16384 + (f * 64 + lane) * 8];
            acc[jt] = __builtin_amdgcn_mfma_f32_16x16x32_bf16(al[t], bh, acc[jt], 0, 0, 0);
            acc[jt] = __builtin_amdgcn_mfma_f32_16x16x32_bf16(ah[t], bl, acc[jt], 0, 0, 0);
            acc[jt] = __builtin_amdgcn_mfma_f32_16x16x32_bf16(ah[t], bh, acc[jt], 0, 0, 0);
        }
    }

    float bv[8];
    #pragma unroll
    for (int jt = 0; jt < 8; ++jt) bv[jt] = biasP[jt * 16 + r];

    #pragma unroll
    for (int i = 0; i < 4; ++i) {
        float m[8];
        float p = 0.0f;
        #pragma unroll
        for (int jt = 0; jt < 8; ++jt) {
            m[jt] = acc[jt][i] + bv[jt];
            p = fmaf(m[jt], m[jt], p);
        }
        p += __shfl_xor(p, 1, 64);
        p += __shfl_xor(p, 2, 64);
        p += __shfl_xor(p, 4, 64);
        p += __shfl_xor(p, 8, 64);        // p = sum_{j<127} mx_j^2
        float n = sqrtf(fmaxf(p, 1e-6f));
        float rr = sinhf(fminf(n, 50.0f)) / n;
        int node = blockIdx.x * 64 + w * 16 + g * 4 + i;
        if (node < NN) {
            #pragma unroll
            for (int jt = 0; jt < 8; ++jt) {
                int j = jt * 16 + r;
                float vv = rr * m[jt];
                ushort us = (j == 127) ? (ushort)0
                          : __builtin_bit_cast(unsigned short, (__bf16)vv);
                hhb[node * 128 + j] = us;
            }
            if (r == 15) hhead[node] = sqrtf(1.0f + rr * rr * p);
        }
    }
}

// ---------------------------------------------------------------------------
// Stage 2+3 fused: segment gather-sum (bf16 rows + fp32 head), Lorentz
// centroid normalize, hyp_act. One wave per node; lane holds comps 2l,2l+1
// (slot 127 = zero pad).
// Concurrency-first design: 8 independent row-gathers in flight per wave
// (8 x 4 cache-lines = 32 lines, Little's-law match to r3's best rate) with
// bf16 rows (half the lines of fp32). col/val scalarize via uniform e
// (s_load -> saddr-form gathers). Head gathered on the vector pipe,
// lane-spread over 8 lanes (8x replication, *0.125 exact). Tail = one
// clamped masked 8-wide iteration (pad slots re-read last row, val=0).
// ---------------------------------------------------------------------------
__global__ __launch_bounds__(256) void centroid_act_kernel(
        const ushort* __restrict__ hhb, const float* __restrict__ hhead,
        const float* __restrict__ val, const int* __restrict__ col,
        const int* __restrict__ rowptr, float* __restrict__ out) {
    const int lane = threadIdx.x & 63;
    const int node = __builtin_amdgcn_readfirstlane(blockIdx.x * 4 + (threadIdx.x >> 6));
    const int lo = rowptr[node], hi = rowptr[node + 1];
    const int ls = lane & 7;

    float s0p = 0.0f, sf0 = 0.0f, sf1 = 0.0f;
    int e = lo;
    for (; e + 8 <= hi; e += 8) {
        // head path: 8 distinct per-lane addresses -> vector gather
        int cs = col[e + ls];
        float vs = val[e + ls];
        s0p = fmaf(vs, hhead[cs], s0p);
        // row path: 8 independent whole-wave 256B row gathers in flight
        int   c[8];
        float v[8];
        #pragma unroll
        for (int k = 0; k < 8; ++k) { c[k] = col[e + k]; v[k] = val[e + k]; }
        uint u[8];
        #pragma unroll
        for (int k = 0; k < 8; ++k)
            u[k] = *(const uint*)&hhb[((long)c[k] << 7) + 2 * lane];
        #pragma unroll
        for (int k = 0; k < 8; ++k) {
            sf0 = fmaf(v[k], __builtin_bit_cast(float, u[k] << 16), sf0);
            sf1 = fmaf(v[k], __builtin_bit_cast(float, u[k] & 0xffff0000u), sf1);
        }
    }
    const int rem = hi - e;
    if (rem > 0) {
        int cs = col[e + ((ls < rem) ? ls : (rem - 1))];
        float vs = (ls < rem) ? val[e + ls] : 0.0f;
        s0p = fmaf(vs, hhead[cs], s0p);
        int   c[8];
        float v[8];
        #pragma unroll
        for (int k = 0; k < 8; ++k) {
            int idx = e + ((k < rem) ? k : (rem - 1));
            c[k] = col[idx];
            v[k] = (k < rem) ? val[idx] : 0.0f;
        }
        uint u[8];
        #pragma unroll
        for (int k = 0; k < 8; ++k)
            u[k] = *(const uint*)&hhb[((long)c[k] << 7) + 2 * lane];
        #pragma unroll
        for (int k = 0; k < 8; ++k) {
            sf0 = fmaf(v[k], __builtin_bit_cast(float, u[k] << 16), sf0);
            sf1 = fmaf(v[k], __builtin_bit_cast(float, u[k] & 0xffff0000u), sf1);
        }
    }

    float s0 = wred64(s0p) * 0.125f;             // each edge counted by 8 groups

    // Lorentz inner = sum_tail s_f^2 - s0^2 (slot 127 pad contributes 0)
    float tsum = wred64(sf0 * sf0 + sf1 * sf1);
    float inner = tsum - s0 * s0;
    float coef = 1.0f / sqrtf(fmaxf(fabsf(inner), 1e-6f));
    float h20 = coef * s0;                       // wave-uniform

    // hyp_act = exp_map_zero(relu(log_map_zero(h2)))
    float dist = arcosh_f(h20);
    float tsq = coef * coef * tsum;              // ||h2 tail||^2, no reduce needed
    float scl = dist / sqrtf(fmaxf(tsq, 1e-6f));
    float u0 = fmaxf(scl * coef * sf0, 0.0f);
    float u1 = fmaxf(scl * coef * sf1, 0.0f);    // lane63: sf1==0 -> u1==0
    float S = wred64(u0 * u0 + u1 * u1);
    float n = sqrtf(fmaxf(S, 1e-6f));
    float r = sinhf(fminf(n, 50.0f)) / n;

    float* op = out + (long)node * 128;
    op[1 + 2 * lane] = r * u0;                       // tail c=2l -> out comp 2l+1
    if (lane < 63) op[2 + 2 * lane] = r * u1;        // tail c=2l+1 -> out comp 2l+2
    else           op[0] = sqrtf(1.0f + r * r * S);  // head
}

extern "C" void kernel_launch(void* const* d_in, const int* in_sizes, int n_in,
                              void* d_out, int out_size, void* d_ws, size_t ws_size,
                              hipStream_t stream) {
    const float* x       = (const float*)d_in[0];
    const float* weight  = (const float*)d_in[1];
    const float* bias    = (const float*)d_in[2];
    const float* adj_val = (const float*)d_in[3];
    const int*   adj_row = (const int*)d_in[4];
    const int*   adj_col = (const int*)d_in[5];
    float* out = (float*)d_out;

    char* ws = (char*)d_ws;
    ushort* hhb    = (ushort*)ws;                   // 12,800,000 B
    float*  hhead  = (float*)(ws + 12800000);       // 200,000 B
    int*    rowptr = (int*)(ws + 13000000);         // 200,004 B
    ushort* WfHi   = (ushort*)(ws + 13200192);      // 32,768 B
    ushort* WfLo   = (ushort*)(ws + 13232960);      // 32,768 B
    float*  biasP  = (float*)(ws + 13265728);       // 512 B

    prep_kernel<<<8, 256, 0, stream>>>(weight, bias, WfHi, WfLo, biasP);
    rowptr_kernel<<<(NE + 255) / 256, 256, 0, stream>>>(adj_row, rowptr);
    transform_kernel<<<(NN + 63) / 64, 256, 0, stream>>>(x, WfHi, biasP, hhb, hhead);
    centroid_act_kernel<<<NN / 4, 256, 0, stream>>>(hhb, hhead, adj_val, adj_col, rowptr, out);
}